// Round 1
// baseline (504.551 us; speedup 1.0000x reference)
//
#include <hip/hip_runtime.h>

// Problem: SHAPE = (L=4, B=64, H=512, W=512), fp32.
// diff[i,j] = sum_{H,W}(amax - aorg);  out = sum_i mean_j 10*exp(-diff)
// Memory-bound: 512 MiB read -> ~85 us floor at 6.3 TB/s.

#define L_DIM 4
#define B_DIM 64
#define HW (512 * 512)                    // 262144 elems per slice, contiguous
#define SLICES (L_DIM * B_DIM)            // 256
#define BLOCKS_PER_SLICE 16
#define THREADS 256
#define CHUNK (HW / BLOCKS_PER_SLICE)     // 16384 elems per block
#define VEC_PER_THREAD (CHUNK / THREADS / 4)  // 16 float4 loads per thread

__global__ __launch_bounds__(THREADS) void ra_partial_kernel(
    const float* __restrict__ amax, const float* __restrict__ aorg,
    float* __restrict__ partials) {
  const int bid = blockIdx.x;                  // 0..4095
  const int slice = bid / BLOCKS_PER_SLICE;
  const int sub = bid % BLOCKS_PER_SLICE;
  const size_t base = (size_t)slice * HW + (size_t)sub * CHUNK;
  const float4* pm = (const float4*)(amax + base);
  const float4* po = (const float4*)(aorg + base);
  const int t = threadIdx.x;

  float acc = 0.0f;
#pragma unroll
  for (int k = 0; k < VEC_PER_THREAD; ++k) {
    float4 m = pm[k * THREADS + t];            // coalesced 16B/lane
    float4 o = po[k * THREADS + t];
    acc += (m.x - o.x) + (m.y - o.y) + (m.z - o.z) + (m.w - o.w);
  }

  // wave-64 shuffle reduction
#pragma unroll
  for (int off = 32; off > 0; off >>= 1) acc += __shfl_down(acc, off, 64);

  __shared__ float smem[THREADS / 64];
  const int lane = t & 63, wave = t >> 6;
  if (lane == 0) smem[wave] = acc;
  __syncthreads();
  if (t == 0) {
    partials[bid] = smem[0] + smem[1] + smem[2] + smem[3];
  }
}

__global__ __launch_bounds__(THREADS) void ra_final_kernel(
    const float* __restrict__ partials, float* __restrict__ out) {
  const int t = threadIdx.x;  // == slice id, 0..255
  float diff = 0.0f;
#pragma unroll
  for (int s = 0; s < BLOCKS_PER_SLICE; ++s)
    diff += partials[t * BLOCKS_PER_SLICE + s];

  float v = 10.0f * expf(-diff) * (1.0f / B_DIM);  // mean over j folded in

#pragma unroll
  for (int off = 32; off > 0; off >>= 1) v += __shfl_down(v, off, 64);

  __shared__ float smem[THREADS / 64];
  const int lane = t & 63, wave = t >> 6;
  if (lane == 0) smem[wave] = v;
  __syncthreads();
  if (t == 0) out[0] = smem[0] + smem[1] + smem[2] + smem[3];
}

extern "C" void kernel_launch(void* const* d_in, const int* in_sizes, int n_in,
                              void* d_out, int out_size, void* d_ws, size_t ws_size,
                              hipStream_t stream) {
  const float* amax = (const float*)d_in[0];
  const float* aorg = (const float*)d_in[1];
  float* out = (float*)d_out;
  float* partials = (float*)d_ws;  // SLICES*BLOCKS_PER_SLICE = 4096 floats

  ra_partial_kernel<<<SLICES * BLOCKS_PER_SLICE, THREADS, 0, stream>>>(
      amax, aorg, partials);
  ra_final_kernel<<<1, THREADS, 0, stream>>>(partials, out);
}

// Round 3
// 465.021 us; speedup vs baseline: 1.0850x; 1.0850x over previous
//
#include <hip/hip_runtime.h>

// Problem: SHAPE = (L=4, B=64, H=512, W=512), fp32.
// diff[i,j] = sum_{H,W}(amax - aorg);  out = sum_i mean_j 10*exp(-diff)
// Memory-bound: 512 MiB read once -> ~85 us floor at 6.3 TB/s achievable.
// R3: fix nontemporal builtin by using native clang vector type (HIP float4
// is a class; builtin needs ext_vector_type). Otherwise same as R2 plan:
// 8192 blocks (32/slice), 8 x 16B loads/thread/input, 4-chain accumulator.

typedef float v4f __attribute__((ext_vector_type(4)));

#define L_DIM 4
#define B_DIM 64
#define HW (512 * 512)                     // 262144 elems per slice, contiguous
#define SLICES (L_DIM * B_DIM)             // 256
#define BLOCKS_PER_SLICE 32
#define GRID (SLICES * BLOCKS_PER_SLICE)   // 8192 blocks
#define THREADS 256
#define CHUNK (HW / BLOCKS_PER_SLICE)      // 8192 elems per block
#define VPT (CHUNK / THREADS / 4)          // 8 v4f loads per thread per input

__global__ __launch_bounds__(THREADS) void ra_partial_kernel(
    const float* __restrict__ amax, const float* __restrict__ aorg,
    float* __restrict__ partials) {
  const int bid = blockIdx.x;                   // 0..8191
  const int slice = bid >> 5;                   // bid / BLOCKS_PER_SLICE
  const int sub = bid & (BLOCKS_PER_SLICE - 1);
  const size_t base = (size_t)slice * HW + (size_t)sub * CHUNK;
  const v4f* pm = (const v4f*)(amax + base);
  const v4f* po = (const v4f*)(aorg + base);
  const int t = threadIdx.x;

  v4f a = {0.f, 0.f, 0.f, 0.f};                 // 4 independent FP chains
#pragma unroll
  for (int k = 0; k < VPT; ++k) {
    v4f m = __builtin_nontemporal_load(&pm[k * THREADS + t]);  // 16B/lane coalesced
    v4f o = __builtin_nontemporal_load(&po[k * THREADS + t]);
    a += m - o;
  }
  float acc = (a.x + a.y) + (a.z + a.w);

  // wave-64 shuffle reduction
#pragma unroll
  for (int off = 32; off > 0; off >>= 1) acc += __shfl_down(acc, off, 64);

  __shared__ float smem[THREADS / 64];
  const int lane = t & 63, wave = t >> 6;
  if (lane == 0) smem[wave] = acc;
  __syncthreads();
  if (t == 0) partials[bid] = smem[0] + smem[1] + smem[2] + smem[3];
}

__global__ __launch_bounds__(THREADS) void ra_final_kernel(
    const float* __restrict__ partials, float* __restrict__ out) {
  const int t = threadIdx.x;  // == slice id, 0..255
  float diff = 0.0f;
#pragma unroll
  for (int s = 0; s < BLOCKS_PER_SLICE; ++s)
    diff += partials[t * BLOCKS_PER_SLICE + s];

  float v = 10.0f * __expf(-diff) * (1.0f / B_DIM);  // mean over j folded in
  // diff is O(1); fast-exp rel err ~1e-5 on O(10) output vs 0.815 threshold: safe.

#pragma unroll
  for (int off = 32; off > 0; off >>= 1) v += __shfl_down(v, off, 64);

  __shared__ float smem[THREADS / 64];
  const int lane = t & 63, wave = t >> 6;
  if (lane == 0) smem[wave] = v;
  __syncthreads();
  if (t == 0) out[0] = smem[0] + smem[1] + smem[2] + smem[3];
}

extern "C" void kernel_launch(void* const* d_in, const int* in_sizes, int n_in,
                              void* d_out, int out_size, void* d_ws, size_t ws_size,
                              hipStream_t stream) {
  const float* amax = (const float*)d_in[0];
  const float* aorg = (const float*)d_in[1];
  float* out = (float*)d_out;
  float* partials = (float*)d_ws;  // GRID = 8192 floats (32 KiB) of scratch

  ra_partial_kernel<<<GRID, THREADS, 0, stream>>>(amax, aorg, partials);
  ra_final_kernel<<<1, THREADS, 0, stream>>>(partials, out);
}